// Round 13
// baseline (171.115 us; speedup 1.0000x reference)
//
#include <hip/hip_runtime.h>

// UniformBottomUpHTMM: T=64 trees, depth 10 (N1=2047, heap layout), C=16,
// M=64, G=16. SINGLE kernel, 512 self-contained blocks, NO d_ws, NO
// inter-block sync. Block b: tree t=b&63, member m=b>>6 computes g=m and m+8.
// b%8 == t%8 -> the 8 blocks of a tree share one XCD; their redundant
// inv_map/x gathers dedup in that XCD's L2 (~8MB HBM total). Params for both
// g's loaded to registers in ONE epoch, softmaxed in-block (r10-verified).
// Kernel touches only d_in + d_out: WRITE_SIZE beyond 4KB is external.
//
// Session findings: r12 proved cross-XCD flag polling must use RMW atomics
// (plain atomic loads spin on stale local-L2 lines ~100us); this round
// removes the barrier entirely to isolate its residual ~60us cost.

#define C_DIM 16
#define M_DIM 64
#define G_DIM 16
#define T_TREES 64
#define N1 2047

__global__ __launch_bounds__(256, 2) void htmm_kernel(
    const int* __restrict__ x,
    const int* __restrict__ inv_map,
    const float* __restrict__ lA,
    const float* __restrict__ lB,
    const float* __restrict__ lPi,
    float* __restrict__ out)
{
    const int bid = blockIdx.x;                // 512 blocks
    const int t   = bid & (T_TREES - 1);       // bid%8 == t%8 -> XCD grouping
    const int m   = bid >> 6;                  // 0..7 -> g = m, m+8
    const int tid = threadIdx.x;

    __shared__ __align__(16) float sA[C_DIM * C_DIM];   // softmax_i A[i,j,g]
    __shared__ __align__(16) float sB[C_DIM * M_DIM];   // softmax_m B[c,m,g]
    __shared__ __align__(16) float sPB[C_DIM * M_DIM];  // Pi[c]*B[c,m]
    __shared__ __align__(16) float sPi[C_DIM];
    __shared__ __align__(16) unsigned char xs[2048];
    __shared__ float buf0[C_DIM * 256];   // L8 betas (SoA stride 256)
    __shared__ float buf1[C_DIM * 128];
    __shared__ float wsum[4];

    const int base = t * N1;

    // ---- epoch 1: ALL independent global loads (tree indices + both g's params)
    int iv[8];
    #pragma unroll
    for (int k = 0; k < 8; ++k) {
        int i = tid + 256 * k;
        iv[k] = inv_map[base + (i < N1 ? i : 0)];
    }
    const int jA = tid >> 4, iA = tid & 15;
    const int cB = tid >> 4, l16 = tid & 15;
    float vA[2], eB[2][4], vPi[2];
    #pragma unroll
    for (int r = 0; r < 2; ++r) {
        const int g = m + r * 8;
        vA[r] = lA[(iA * C_DIM + jA) * G_DIM + g];
        eB[r][0] = lB[(cB * M_DIM + l16 +  0) * G_DIM + g];
        eB[r][1] = lB[(cB * M_DIM + l16 + 16) * G_DIM + g];
        eB[r][2] = lB[(cB * M_DIM + l16 + 32) * G_DIM + g];
        eB[r][3] = lB[(cB * M_DIM + l16 + 48) * G_DIM + g];
        vPi[r] = lPi[(tid & 15) * G_DIM + g];
    }

    // ---- epoch 2: dependent symbol gather ----
    int xv8[8];
    #pragma unroll
    for (int k = 0; k < 8; ++k) xv8[k] = x[iv[k]];
    #pragma unroll
    for (int k = 0; k < 8; ++k) {
        int i = tid + 256 * k;
        if (i < N1) xs[i] = (unsigned char)xv8[k];
    }

    for (int rep = 0; rep < 2; ++rep) {
        const int g = m + rep * 8;

        if (rep == 1) __syncthreads();   // pass of rep0 fully done before overwrite

        {   // A: softmax over i within each column jA
            float v = vA[rep];
            float mx = v;
            #pragma unroll
            for (int q = 1; q < 16; q <<= 1) mx = fmaxf(mx, __shfl_xor(mx, q, 16));
            float e = __expf(v - mx);
            float s = e;
            #pragma unroll
            for (int q = 1; q < 16; q <<= 1) s += __shfl_xor(s, q, 16);
            sA[iA * C_DIM + jA] = e / s;
        }
        {   // B: softmax over m within row cB (4 symbols per lane)
            float e0 = eB[rep][0], e1 = eB[rep][1], e2 = eB[rep][2], e3 = eB[rep][3];
            float mx = fmaxf(fmaxf(e0, e1), fmaxf(e2, e3));
            #pragma unroll
            for (int q = 1; q < 16; q <<= 1) mx = fmaxf(mx, __shfl_xor(mx, q, 16));
            e0 = __expf(e0 - mx); e1 = __expf(e1 - mx);
            e2 = __expf(e2 - mx); e3 = __expf(e3 - mx);
            float s = e0 + e1 + e2 + e3;
            #pragma unroll
            for (int q = 1; q < 16; q <<= 1) s += __shfl_xor(s, q, 16);
            float inv = 1.f / s;
            sB[cB * M_DIM + l16 +  0] = e0 * inv;
            sB[cB * M_DIM + l16 + 16] = e1 * inv;
            sB[cB * M_DIM + l16 + 32] = e2 * inv;
            sB[cB * M_DIM + l16 + 48] = e3 * inv;
        }
        {   // Pi: softmax over c (each 16-lane segment; same result)
            float v = vPi[rep];
            float mx = v;
            #pragma unroll
            for (int q = 1; q < 16; q <<= 1) mx = fmaxf(mx, __shfl_xor(mx, q, 16));
            float e = __expf(v - mx);
            float s = e;
            #pragma unroll
            for (int q = 1; q < 16; q <<= 1) s += __shfl_xor(s, q, 16);
            if (tid < C_DIM) sPi[tid] = e / s;
        }
        __syncthreads();

        // sPB = Pi[c] * B[c][m]
        {
            float pc = sPi[cB];
            sPB[cB * M_DIM + l16 +  0] = pc * sB[cB * M_DIM + l16 +  0];
            sPB[cB * M_DIM + l16 + 16] = pc * sB[cB * M_DIM + l16 + 16];
            sPB[cB * M_DIM + l16 + 32] = pc * sB[cB * M_DIM + l16 + 32];
            sPB[cB * M_DIM + l16 + 48] = pc * sB[cB * M_DIM + l16 + 48];
        }
        __syncthreads();

        float ll = 0.f;

        // ---- fused leaves (L10) + L9 + L8: one L8 node per thread ----
        {
            const int idx = tid;
            const int p8  = 255 + idx;
            float s8[C_DIM];
            #pragma unroll
            for (int k = 0; k < C_DIM; ++k) s8[k] = 0.f;
            #pragma unroll
            for (int c9 = 0; c9 < 2; ++c9) {
                const int p9 = 2 * p8 + 1 + c9;
                float s9[C_DIM];
                #pragma unroll
                for (int k = 0; k < C_DIM; ++k) s9[k] = 0.f;
                #pragma unroll
                for (int cl = 0; cl < 2; ++cl) {
                    const int xv = xs[2 * p9 + 1 + cl];
                    float b[C_DIM]; float nu = 0.f;
                    #pragma unroll
                    for (int k = 0; k < C_DIM; ++k) {
                        b[k] = sPB[k * M_DIM + xv];
                        nu += b[k];
                    }
                    float inv = 0.5f / nu;
                    #pragma unroll
                    for (int k = 0; k < C_DIM; ++k) s9[k] += b[k] * inv;
                    ll += __logf(nu);
                }
                const int xv = xs[p9];
                float bp[C_DIM]; float nu = 0.f;
                #pragma unroll
                for (int i = 0; i < C_DIM; ++i) {
                    float ti = 0.f;
                    #pragma unroll
                    for (int j = 0; j < C_DIM; ++j) ti += sA[i * C_DIM + j] * s9[j];
                    bp[i] = ti * sB[i * M_DIM + xv];
                    nu += bp[i];
                }
                ll += __logf(nu);
                float inv = 0.5f / nu;
                #pragma unroll
                for (int k = 0; k < C_DIM; ++k) s8[k] += bp[k] * inv;
            }
            const int xv = xs[p8];
            float bp[C_DIM]; float nu = 0.f;
            #pragma unroll
            for (int i = 0; i < C_DIM; ++i) {
                float ti = 0.f;
                #pragma unroll
                for (int j = 0; j < C_DIM; ++j) ti += sA[i * C_DIM + j] * s8[j];
                bp[i] = ti * sB[i * M_DIM + xv];
                nu += bp[i];
            }
            ll += __logf(nu);
            float inv = 1.f / nu;
            #pragma unroll
            for (int k = 0; k < C_DIM; ++k) buf0[k * 256 + idx] = bp[k] * inv;
        }
        __syncthreads();

        // ---- L7: 128 nodes ----
        if (tid < 128) {
            const int idx = tid;
            float s[C_DIM];
            #pragma unroll
            for (int j = 0; j < C_DIM; ++j) {
                float2 cv = ((const float2*)(buf0 + j * 256))[idx];
                s[j] = 0.5f * (cv.x + cv.y);
            }
            const int xv = xs[127 + idx];
            float bp[C_DIM]; float nu = 0.f;
            #pragma unroll
            for (int i = 0; i < C_DIM; ++i) {
                float ti = 0.f;
                #pragma unroll
                for (int j = 0; j < C_DIM; ++j) ti += sA[i * C_DIM + j] * s[j];
                bp[i] = ti * sB[i * M_DIM + xv];
                nu += bp[i];
            }
            ll += __logf(nu);
            float inv = 1.f / nu;
            #pragma unroll
            for (int i = 0; i < C_DIM; ++i) buf1[i * 128 + idx] = bp[i] * inv;
        }
        __syncthreads();

        // ---- L6..L0 (64..1 nodes): wave 0 only, LDS fences not barriers ----
        if (tid < 64) {
            float* cur = buf1; int cs = 128;
            float* nxt = buf0; int ns = 256;
            for (int cnt = 64; cnt >= 1; cnt >>= 1) {
                if (tid < cnt) {
                    const int idx = tid;
                    float s[C_DIM];
                    #pragma unroll
                    for (int j = 0; j < C_DIM; ++j) {
                        float a  = cur[j * cs + 2 * idx];
                        float b2 = cur[j * cs + 2 * idx + 1];
                        s[j] = 0.5f * (a + b2);
                    }
                    const int xv = xs[cnt - 1 + idx];
                    float bp[C_DIM]; float nu = 0.f;
                    #pragma unroll
                    for (int i = 0; i < C_DIM; ++i) {
                        float ti = 0.f;
                        #pragma unroll
                        for (int j = 0; j < C_DIM; ++j) ti += sA[i * C_DIM + j] * s[j];
                        bp[i] = ti * sB[i * M_DIM + xv];
                        nu += bp[i];
                    }
                    ll += __logf(nu);
                    float inv = 1.f / nu;
                    #pragma unroll
                    for (int i = 0; i < C_DIM; ++i) nxt[i * ns + idx] = bp[i] * inv;
                }
                asm volatile("s_waitcnt lgkmcnt(0)" ::: "memory");
                __builtin_amdgcn_wave_barrier();
                float* tp = cur; cur = nxt; nxt = tp;
                int ts = cs; cs = ns; ns = ts;
            }
        }

        // ---- reduce ll across block ----
        float v = ll;
        #pragma unroll
        for (int off = 32; off > 0; off >>= 1) v += __shfl_down(v, off, 64);
        if ((tid & 63) == 0) wsum[tid >> 6] = v;
        __syncthreads();
        if (tid == 0) out[t * G_DIM + g] = wsum[0] + wsum[1] + wsum[2] + wsum[3];
    }
}

extern "C" void kernel_launch(void* const* d_in, const int* in_sizes, int n_in,
                              void* d_out, int out_size, void* d_ws, size_t ws_size,
                              hipStream_t stream) {
    const int*   x       = (const int*)d_in[0];
    const int*   inv_map = (const int*)d_in[6];
    const float* lA      = (const float*)d_in[7];
    const float* lB      = (const float*)d_in[8];
    const float* lPi     = (const float*)d_in[9];
    float* out = (float*)d_out;

    htmm_kernel<<<dim3(512), dim3(256), 0, stream>>>(
        x, inv_map, lA, lB, lPi, out);
}

// Round 14
// 168.143 us; speedup vs baseline: 1.0177x; 1.0177x over previous
//
#include <hip/hip_runtime.h>

// UniformBottomUpHTMM: T=64 trees, depth 10 (N1=2047, heap layout), C=16,
// M=64, G=16. SINGLE kernel, 512 blocks, device barrier in which EVERY
// signal/poll is an atomic RMW. KEY gfx950 FINDING (r8-r12): plain
// agent-scope atomic loads/stores used as barrier flags can be served STALE
// from the non-coherent per-XCD L2 for ~100+us (until eviction); atomic RMWs
// always traverse the coherent point. RMW-izing the barrier cut 50us.
//   arrival: atomicExch(&flags[bid],1)   (512 distinct words)
//   sweep:   block 0 polls via atomicOr(&flags[i],0) (RMW read)
//   release: 64 words spaced 64B, atomicExch to set, atomicOr to poll
// Phase A: xs gather (coalesced, once) + per-g softmax blobs -> d_ws.
// Phase B: block=(t,gh), bid%8==t%8 keeps same-tree blocks on one XCD;
//          full LDS bottom-up pass for g=gh and gh+8.
//
// Session floor (r12/r13 A/B): window ~104us with ~16.5us VALU; the rest is
// the kernel's loads queueing behind ~150MB of harness poison/restore
// writeback (WRITE_SIZE ~81MB in a window where this kernel writes 4KB).
// Best measured total: 166.8us (this exact source, r12).

#define C_DIM 16
#define M_DIM 64
#define G_DIM 16
#define T_TREES 64
#define N1 2047

#define PAR_STRIDE 1536
#define XS_BYTE_OFF (G_DIM * PAR_STRIDE * 4)     // 98304
#define BAR_BYTE_OFF (512 * 1024)                // barrier region in d_ws
#define NBLOCKS 512

__global__ __launch_bounds__(256, 2) void htmm_fused(
    const int* __restrict__ x,
    const int* __restrict__ inv_map,
    const float* __restrict__ lA,
    const float* __restrict__ lB,
    const float* __restrict__ lPi,
    float* __restrict__ ws,
    float* __restrict__ out)
{
    const int bid = blockIdx.x;      // 512 blocks, all co-resident (cap 1024)
    const int tid = threadIdx.x;

    __shared__ __align__(16) float sA[C_DIM * C_DIM];
    __shared__ __align__(16) float sB[C_DIM * M_DIM];
    __shared__ __align__(16) float sPi[C_DIM];
    __shared__ __align__(16) unsigned char xs[2048];
    __shared__ float buf0[C_DIM * 256];   // L8 betas (SoA stride 256)
    __shared__ float buf1[C_DIM * 128];
    __shared__ float wsum[4];

    // ================= Phase A =================
    {   // xs gather: 512*256 = 131072 slots = 64 trees * 2048 (coalesced)
        int slot = bid * 256 + tid;
        int t = slot >> 11, i = slot & 2047;
        unsigned char v = 0;
        if (i < N1) v = (unsigned char)x[inv_map[t * N1 + i]];
        ((unsigned char*)ws)[XS_BYTE_OFF + slot] = v;
    }
    if (bid < G_DIM) {   // params: one g per block
        const int g = bid;
        float* pg = ws + g * PAR_STRIDE;
        {   // A: softmax over i within 16-lane segments
            int j = tid >> 4, i = tid & 15;
            float v = lA[(i * C_DIM + j) * G_DIM + g];
            float mx = v;
            #pragma unroll
            for (int m = 1; m < 16; m <<= 1) mx = fmaxf(mx, __shfl_xor(mx, m, 16));
            float e = __expf(v - mx);
            float s = e;
            #pragma unroll
            for (int m = 1; m < 16; m <<= 1) s += __shfl_xor(s, m, 16);
            pg[i * C_DIM + j] = e / s;
        }
        {   // B: softmax over m, row c, 4 symbols per lane
            int c = tid >> 4, l16 = tid & 15;
            float e0 = lB[(c * M_DIM + l16 +  0) * G_DIM + g];
            float e1 = lB[(c * M_DIM + l16 + 16) * G_DIM + g];
            float e2 = lB[(c * M_DIM + l16 + 32) * G_DIM + g];
            float e3 = lB[(c * M_DIM + l16 + 48) * G_DIM + g];
            float mx = fmaxf(fmaxf(e0, e1), fmaxf(e2, e3));
            #pragma unroll
            for (int m = 1; m < 16; m <<= 1) mx = fmaxf(mx, __shfl_xor(mx, m, 16));
            e0 = __expf(e0 - mx); e1 = __expf(e1 - mx);
            e2 = __expf(e2 - mx); e3 = __expf(e3 - mx);
            float s = e0 + e1 + e2 + e3;
            #pragma unroll
            for (int m = 1; m < 16; m <<= 1) s += __shfl_xor(s, m, 16);
            float inv = 1.f / s;
            pg[256 + c * M_DIM + l16 +  0] = e0 * inv;
            pg[256 + c * M_DIM + l16 + 16] = e1 * inv;
            pg[256 + c * M_DIM + l16 + 32] = e2 * inv;
            pg[256 + c * M_DIM + l16 + 48] = e3 * inv;
        }
        if (tid < C_DIM) {  // Pi
            float v = lPi[tid * G_DIM + g];
            float mx = v;
            #pragma unroll
            for (int m = 1; m < 16; m <<= 1) mx = fmaxf(mx, __shfl_xor(mx, m, 16));
            float e = __expf(v - mx);
            float s = e;
            #pragma unroll
            for (int m = 1; m < 16; m <<= 1) s += __shfl_xor(s, m, 16);
            pg[1280 + tid] = e / s;
        }
    }

    // ========== device barrier: ALL signals/polls are coherent RMWs ==========
    {
        unsigned int* flags   = (unsigned int*)((char*)ws + BAR_BYTE_OFF);  // [512]
        unsigned int* release = flags + NBLOCKS;   // 64 words, stride 16 (64B)
        __syncthreads();                           // phase-A done in this block
        if (tid == 0) {
            __threadfence();                       // release phase-A writes
            atomicExch(&flags[bid], 1u);           // coherent arrival
        }
        if (bid == 0) {
            // 256 threads sweep 512 distinct flags via RMW reads
            for (;;) {
                unsigned int a = atomicOr(&flags[tid], 0u);
                unsigned int b = atomicOr(&flags[tid + 256], 0u);
                bool ready = (a == 1u) && (b == 1u);
                if (__syncthreads_count(ready) == 256) break;
                __builtin_amdgcn_s_sleep(8);
            }
            __threadfence();
            if (tid < 64)   // fan-out: 64 release words on distinct lines
                atomicExch(&release[tid * 16], 1u);
        } else if (tid == 0) {
            unsigned int* myrel = &release[(bid & 63) * 16];  // 8 pollers/word
            while (atomicOr(myrel, 0u) != 1u)
                __builtin_amdgcn_s_sleep(8);
            __threadfence();                       // acquire others' writes
        }
        __syncthreads();
    }

    // ================= Phase B =================
    const int gh = bid >> 6;          // 0..7 -> g = gh, gh+8
    const int t  = bid & (T_TREES-1); // bid%8 == t%8 -> same-tree blocks share XCD

    // tree symbols: load once (2KB, coalesced)
    if (tid < 128)
        ((int4*)xs)[tid] =
            ((const int4*)((const unsigned char*)ws + XS_BYTE_OFF + t * 2048))[tid];

    for (int rep = 0; rep < 2; ++rep) {
        const int g = gh + rep * 8;
        {   // compact param loads for this g
            const float* pg = ws + g * PAR_STRIDE;
            ((float4*)sB)[tid] = ((const float4*)(pg + 256))[tid];
            if (tid < 64)  ((float4*)sA)[tid]  = ((const float4*)pg)[tid];
            if (tid < 4)   ((float4*)sPi)[tid] = ((const float4*)(pg + 1280))[tid];
        }
        __syncthreads();

        float ll = 0.f;

        // ---- fused leaves (L10) + L9 + L8: one L8 node per thread ----
        {
            const int idx = tid;
            const int p8  = 255 + idx;
            float s8[C_DIM];
            #pragma unroll
            for (int k = 0; k < C_DIM; ++k) s8[k] = 0.f;
            #pragma unroll
            for (int c9 = 0; c9 < 2; ++c9) {
                const int p9 = 2 * p8 + 1 + c9;
                float s9[C_DIM];
                #pragma unroll
                for (int k = 0; k < C_DIM; ++k) s9[k] = 0.f;
                #pragma unroll
                for (int cl = 0; cl < 2; ++cl) {
                    const int xv = xs[2 * p9 + 1 + cl];
                    float b[C_DIM]; float nu = 0.f;
                    #pragma unroll
                    for (int k = 0; k < C_DIM; ++k) {
                        b[k] = sPi[k] * sB[k * M_DIM + xv];
                        nu += b[k];
                    }
                    float inv = 0.5f / nu;
                    #pragma unroll
                    for (int k = 0; k < C_DIM; ++k) s9[k] += b[k] * inv;
                    ll += __logf(nu);
                }
                const int xv = xs[p9];
                float bp[C_DIM]; float nu = 0.f;
                #pragma unroll
                for (int i = 0; i < C_DIM; ++i) {
                    float ti = 0.f;
                    #pragma unroll
                    for (int j = 0; j < C_DIM; ++j) ti += sA[i * C_DIM + j] * s9[j];
                    bp[i] = ti * sB[i * M_DIM + xv];
                    nu += bp[i];
                }
                ll += __logf(nu);
                float inv = 0.5f / nu;
                #pragma unroll
                for (int k = 0; k < C_DIM; ++k) s8[k] += bp[k] * inv;
            }
            const int xv = xs[p8];
            float bp[C_DIM]; float nu = 0.f;
            #pragma unroll
            for (int i = 0; i < C_DIM; ++i) {
                float ti = 0.f;
                #pragma unroll
                for (int j = 0; j < C_DIM; ++j) ti += sA[i * C_DIM + j] * s8[j];
                bp[i] = ti * sB[i * M_DIM + xv];
                nu += bp[i];
            }
            ll += __logf(nu);
            float inv = 1.f / nu;
            #pragma unroll
            for (int k = 0; k < C_DIM; ++k) buf0[k * 256 + idx] = bp[k] * inv;
        }
        __syncthreads();

        // ---- L7: 128 nodes ----
        if (tid < 128) {
            const int idx = tid;
            float s[C_DIM];
            #pragma unroll
            for (int j = 0; j < C_DIM; ++j) {
                float2 cv = ((const float2*)(buf0 + j * 256))[idx];
                s[j] = 0.5f * (cv.x + cv.y);
            }
            const int xv = xs[127 + idx];
            float bp[C_DIM]; float nu = 0.f;
            #pragma unroll
            for (int i = 0; i < C_DIM; ++i) {
                float ti = 0.f;
                #pragma unroll
                for (int j = 0; j < C_DIM; ++j) ti += sA[i * C_DIM + j] * s[j];
                bp[i] = ti * sB[i * M_DIM + xv];
                nu += bp[i];
            }
            ll += __logf(nu);
            float inv = 1.f / nu;
            #pragma unroll
            for (int i = 0; i < C_DIM; ++i) buf1[i * 128 + idx] = bp[i] * inv;
        }
        __syncthreads();

        // ---- L6..L0 (64..1 nodes): wave 0 only, LDS fences not barriers ----
        if (tid < 64) {
            float* cur = buf1; int cs = 128;
            float* nxt = buf0; int ns = 256;
            for (int cnt2 = 64; cnt2 >= 1; cnt2 >>= 1) {
                if (tid < cnt2) {
                    const int idx = tid;
                    float s[C_DIM];
                    #pragma unroll
                    for (int j = 0; j < C_DIM; ++j) {
                        float a  = cur[j * cs + 2 * idx];
                        float b2 = cur[j * cs + 2 * idx + 1];
                        s[j] = 0.5f * (a + b2);
                    }
                    const int xv = xs[cnt2 - 1 + idx];
                    float bp[C_DIM]; float nu = 0.f;
                    #pragma unroll
                    for (int i = 0; i < C_DIM; ++i) {
                        float ti = 0.f;
                        #pragma unroll
                        for (int j = 0; j < C_DIM; ++j) ti += sA[i * C_DIM + j] * s[j];
                        bp[i] = ti * sB[i * M_DIM + xv];
                        nu += bp[i];
                    }
                    ll += __logf(nu);
                    float inv = 1.f / nu;
                    #pragma unroll
                    for (int i = 0; i < C_DIM; ++i) nxt[i * ns + idx] = bp[i] * inv;
                }
                asm volatile("s_waitcnt lgkmcnt(0)" ::: "memory");
                __builtin_amdgcn_wave_barrier();
                float* tp = cur; cur = nxt; nxt = tp;
                int ts = cs; cs = ns; ns = ts;
            }
        }

        // ---- reduce ll across block ----
        float v = ll;
        #pragma unroll
        for (int off = 32; off > 0; off >>= 1) v += __shfl_down(v, off, 64);
        if ((tid & 63) == 0) wsum[tid >> 6] = v;
        __syncthreads();
        if (tid == 0) out[t * G_DIM + g] = wsum[0] + wsum[1] + wsum[2] + wsum[3];
        __syncthreads();   // buffers/params reused next rep
    }
}

extern "C" void kernel_launch(void* const* d_in, const int* in_sizes, int n_in,
                              void* d_out, int out_size, void* d_ws, size_t ws_size,
                              hipStream_t stream) {
    const int*   x       = (const int*)d_in[0];
    const int*   inv_map = (const int*)d_in[6];
    const float* lA      = (const float*)d_in[7];
    const float* lB      = (const float*)d_in[8];
    const float* lPi     = (const float*)d_in[9];
    float* ws  = (float*)d_ws;
    float* out = (float*)d_out;

    htmm_fused<<<dim3(NBLOCKS), dim3(256), 0, stream>>>(
        x, inv_map, lA, lB, lPi, ws, out);
}